// Round 1
// baseline (1079.503 us; speedup 1.0000x reference)
//
#include <hip/hip_runtime.h>

#define F 32
#define S 16

// ---------------------------------------------------------------------------
// Edge kernel: one thread per edge.
// msg[e,o] = sum_{s,f} e[e,s] * x[src[e],f] * W[s, f*F+o]  + sum_f x[f]*B[f*F+o]
// scatter-add into agg[dst[e], :].
// W/B indices are wave-uniform -> scalar loads; x row + acc live in VGPRs.
// ---------------------------------------------------------------------------
__global__ __launch_bounds__(256) void ecc_edge(
    const float* __restrict__ x,    // (N,F)
    const float* __restrict__ ef,   // (E,S)
    const int*   __restrict__ src,
    const int*   __restrict__ dst,
    const float* __restrict__ W,    // (S, F*F)
    const float* __restrict__ B,    // (F*F)
    float* __restrict__ agg,        // (N,F), pre-zeroed
    int E)
{
    int e = blockIdx.x * blockDim.x + threadIdx.x;
    if (e >= E) return;

    const int sn = src[e];
    const int dn = dst[e];

    // load x[src] row into registers (vectorized)
    float xr[F];
    const float4* xp = (const float4*)(x + (size_t)sn * F);
    #pragma unroll
    for (int i = 0; i < F / 4; ++i) {
        float4 v = xp[i];
        xr[4*i+0] = v.x; xr[4*i+1] = v.y; xr[4*i+2] = v.z; xr[4*i+3] = v.w;
    }

    float acc[F];
    #pragma unroll
    for (int o = 0; o < F; ++o) acc[o] = 0.0f;

    const float* erow = ef + (size_t)e * S;
    for (int s = 0; s < S; ++s) {
        const float es = erow[s];            // per-lane load, L1-resident
        const float* Ws = W + s * (F * F);   // uniform base
        #pragma unroll
        for (int f = 0; f < F; ++f) {
            const float z = es * xr[f];
            #pragma unroll
            for (int o = 0; o < F; ++o)
                acc[o] = fmaf(z, Ws[f * F + o], acc[o]);  // Ws[..] uniform -> s_load
        }
    }

    // fgn bias term: k += B, so msg += sum_f x[f] * B[f*F+o]
    #pragma unroll
    for (int f = 0; f < F; ++f) {
        const float xf = xr[f];
        #pragma unroll
        for (int o = 0; o < F; ++o)
            acc[o] = fmaf(xf, B[f * F + o], acc[o]);
    }

    float* ap = agg + (size_t)dn * F;
    #pragma unroll
    for (int o = 0; o < F; ++o)
        atomicAdd(ap + o, acc[o]);
}

// ---------------------------------------------------------------------------
// Node kernel: h[n,o] = relu(agg[n,o] + bias[o] + sum_f x[n,f]*root[f,o])
// In-place on agg is safe (each thread touches only its own element).
// ---------------------------------------------------------------------------
__global__ __launch_bounds__(256) void ecc_node(
    const float* __restrict__ xin,   // (N,F)
    const float* __restrict__ root,  // (F,F)
    const float* __restrict__ bias,  // (F)
    float* __restrict__ h,           // (N,F): reads agg, writes relu'd h
    int N)
{
    int t = blockIdx.x * blockDim.x + threadIdx.x;
    if (t >= N * F) return;
    const int n = t >> 5;       // /F
    const int o = t & (F - 1);  // %F
    const float* xrow = xin + (size_t)n * F;
    float v = h[t] + bias[o];
    #pragma unroll
    for (int f = 0; f < F; ++f)
        v = fmaf(xrow[f], root[f * F + o], v);
    h[t] = fmaxf(v, 0.0f);
}

// ---------------------------------------------------------------------------
// Pool: pooled[c] = sum_n h[n,c]; per-block channel partials then 32 atomics.
// ---------------------------------------------------------------------------
__global__ __launch_bounds__(256) void pool_kernel(
    const float* __restrict__ h, float* __restrict__ pooled, int N)
{
    const int c = threadIdx.x & (F - 1);
    const int rowsPerBlock = 256 / F;  // 8
    float p = 0.0f;
    for (int n = blockIdx.x * rowsPerBlock + (threadIdx.x >> 5);
         n < N; n += gridDim.x * rowsPerBlock)
        p += h[(size_t)n * F + c];

    __shared__ float red[256];
    red[threadIdx.x] = p;
    __syncthreads();
    for (int off = 128; off >= F; off >>= 1) {
        if (threadIdx.x < off) red[threadIdx.x] += red[threadIdx.x + off];
        __syncthreads();
    }
    if (threadIdx.x < F) atomicAdd(&pooled[threadIdx.x], red[threadIdx.x]);
}

// ---------------------------------------------------------------------------
// Final: out[0] = sum_c pooled[c]*dense_w[c] + dense_b[0]
// ---------------------------------------------------------------------------
__global__ void final_kernel(
    const float* __restrict__ pooled,
    const float* __restrict__ dw,
    const float* __restrict__ db,
    float* __restrict__ out)
{
    const int o = threadIdx.x;  // one wave (64)
    float v = (o < F) ? pooled[o] * dw[o] : 0.0f;
    #pragma unroll
    for (int off = 32; off > 0; off >>= 1)
        v += __shfl_down(v, off, 64);
    if (o == 0) out[0] = v + db[0];
}

// ---------------------------------------------------------------------------
extern "C" void kernel_launch(void* const* d_in, const int* in_sizes, int n_in,
                              void* d_out, int out_size, void* d_ws, size_t ws_size,
                              hipStream_t stream) {
    const float* x      = (const float*)d_in[0];
    const float* efeat  = (const float*)d_in[1];
    const int*   src    = (const int*)d_in[2];
    const int*   dst    = (const int*)d_in[3];
    const float* fgn_w1 = (const float*)d_in[4];
    const float* fgn_b1 = (const float*)d_in[5];
    const float* root1  = (const float*)d_in[6];
    const float* bias1  = (const float*)d_in[7];
    const float* fgn_w2 = (const float*)d_in[8];
    const float* fgn_b2 = (const float*)d_in[9];
    const float* root2  = (const float*)d_in[10];
    const float* bias2  = (const float*)d_in[11];
    const float* dense_w = (const float*)d_in[12];
    const float* dense_b = (const float*)d_in[13];

    const int N = in_sizes[0] / F;
    const int E = in_sizes[2];

    // workspace: agg1 (N*F) | agg2 (N*F) | pooled (F)
    float* agg1   = (float*)d_ws;
    float* agg2   = agg1 + (size_t)N * F;
    float* pooled = agg2 + (size_t)N * F;

    // zero agg1+agg2+pooled in one stream-ordered memset (graph-capturable)
    hipMemsetAsync(d_ws, 0, ((size_t)2 * N * F + F) * sizeof(float), stream);

    const int edgeBlocks = (E + 255) / 256;
    const int nodeBlocks = (N * F + 255) / 256;

    // ---- layer 1 ----
    ecc_edge<<<edgeBlocks, 256, 0, stream>>>(x, efeat, src, dst, fgn_w1, fgn_b1, agg1, E);
    ecc_node<<<nodeBlocks, 256, 0, stream>>>(x, root1, bias1, agg1, N);   // agg1 -> h1 in-place

    // ---- layer 2 ----
    ecc_edge<<<edgeBlocks, 256, 0, stream>>>(agg1, efeat, src, dst, fgn_w2, fgn_b2, agg2, E);
    ecc_node<<<nodeBlocks, 256, 0, stream>>>(agg1, root2, bias2, agg2, N); // agg2 -> h2 in-place

    // ---- pool + dense ----
    pool_kernel<<<512, 256, 0, stream>>>(agg2, pooled, N);
    final_kernel<<<1, 64, 0, stream>>>(pooled, dense_w, dense_b, (float*)d_out);
}